// Round 4
// baseline (219.613 us; speedup 1.0000x reference)
//
#include <hip/hip_runtime.h>
#include <hip/hip_bf16.h>

#define CS 384
#define CH 32
#define CZ 128
#define LL 384
#define NL 1536   // N*L
#define EPS 1e-5f

typedef float v2f __attribute__((ext_vector_type(2)));
typedef float v4f __attribute__((ext_vector_type(4)));

// ---------------- Kernel 1: LayerNorm + A = sn@W1+b1, B = sn@W2+b2 ------------
__global__ __launch_bounds__(128) void k_ln_ab(
    const float* __restrict__ s, const float* __restrict__ g, const float* __restrict__ be,
    const float* __restrict__ W1, const float* __restrict__ b1,
    const float* __restrict__ W2, const float* __restrict__ b2,
    float* __restrict__ A, float* __restrict__ B)
{
    const int row = blockIdx.x;
    const int t   = threadIdx.x;
    const int wid = t >> 6, lane = t & 63;
    const float* srow = s + (size_t)row * CS;

    __shared__ float sn[CS];
    __shared__ float red[2];
    __shared__ float part[128];

    float x0 = srow[t], x1 = srow[t + 128], x2 = srow[t + 256];

    // mean
    float p = x0 + x1 + x2;
    #pragma unroll
    for (int o = 32; o > 0; o >>= 1) p += __shfl_down(p, o);
    if (lane == 0) red[wid] = p;
    __syncthreads();
    const float mu = (red[0] + red[1]) * (1.0f / CS);
    __syncthreads();

    // variance
    float d0 = x0 - mu, d1 = x1 - mu, d2 = x2 - mu;
    float q = d0 * d0 + d1 * d1 + d2 * d2;
    #pragma unroll
    for (int o = 32; o > 0; o >>= 1) q += __shfl_down(q, o);
    if (lane == 0) red[wid] = q;
    __syncthreads();
    const float var = (red[0] + red[1]) * (1.0f / CS);
    const float rstd = rsqrtf(var + EPS);

    sn[t]       = d0 * rstd * g[t]       + be[t];
    sn[t + 128] = d1 * rstd * g[t + 128] + be[t + 128];
    sn[t + 256] = d2 * rstd * g[t + 256] + be[t + 256];
    __syncthreads();

    // matvec: all 128 threads. t -> (half = t>>6, mat = (t>>5)&1, h = t&31)
    {
        const int h    = t & 31;
        const int mat  = (t >> 5) & 1;
        const int half = t >> 6;
        const float* W = mat ? W2 : W1;
        float acc = 0.0f;
        const int c0 = half * (CS / 2);
        #pragma unroll 8
        for (int c = c0; c < c0 + CS / 2; ++c)
            acc += sn[c] * W[c * CH + h];
        part[t] = acc;
    }
    __syncthreads();
    if (t < 64) {
        const int h   = t & 31;
        const int mat = t >> 5;
        const float v = part[t] + part[t + 64] + (mat ? b2[h] : b1[h]);
        (mat ? B : A)[(size_t)row * CH + h] = v;
    }
}

// ---------------- Kernel 2: M[r,d,z] = sum_c A[r,c] * Wo[c,d,z] --------------
// GEMM: [NL,32] x [32,4096] -> [NL,4096]; 16 rows/block, float4 cols.
__global__ __launch_bounds__(256) void k_m(
    const float* __restrict__ A, const float* __restrict__ Wo, float* __restrict__ M)
{
    const int t  = threadIdx.x;
    const int r0 = blockIdx.x * 16;
    __shared__ float Al[16][CH];
    Al[t >> 5][t & 31]       = A[(size_t)(r0 + (t >> 5)) * CH + (t & 31)];
    Al[(t >> 5) + 8][t & 31] = A[(size_t)(r0 + (t >> 5) + 8) * CH + (t & 31)];
    __syncthreads();

    const v4f* Wo4 = (const v4f*)Wo;      // 1024 float4 per c-row
    v4f*       M4  = (v4f*)M;

    for (int g4 = t; g4 < 1024; g4 += 256) {
        v4f acc[16];
        #pragma unroll
        for (int r = 0; r < 16; ++r) acc[r] = (v4f)(0.f);
        #pragma unroll 4
        for (int c = 0; c < CH; ++c) {
            const v4f wv = Wo4[(size_t)c * 1024 + g4];
            #pragma unroll
            for (int r = 0; r < 16; ++r)
                acc[r] += Al[r][c] * wv;
        }
        #pragma unroll
        for (int r = 0; r < 16; ++r)
            M4[(size_t)(r0 + r) * 1024 + g4] = acc[r];
    }
}

// ---------------- Kernel 3: out[r,j,z] = sum_d B[n,j,d]*M[r,d,z] + bo[z] -----
// One block (4 waves) per r. Wave w owns j in [96w, 96w+96) -> b-row is
// wave-uniform (scalarizable). Thread owns z-pair (v2f) -> packed fp32 FMA
// and v2f nontemporal stores (512 B per wave-store).
__global__ __launch_bounds__(256) void k_out(
    const float* __restrict__ B, const float* __restrict__ M,
    const float* __restrict__ bo, float* __restrict__ out)
{
    const int r  = blockIdx.x;
    const int t  = threadIdx.x;
    const int tz = t & 63;          // z = 2*tz
    const int tj = t >> 6;          // wave id 0..3
    const int n  = r / LL;

    v2f m[CH];
    {
        const v2f* Mr = (const v2f*)(M + (size_t)r * (CH * CZ));
        #pragma unroll
        for (int d = 0; d < CH; ++d) m[d] = Mr[d * 64 + tz];
    }
    v2f bz;
    bz.x = bo[2 * tz];
    bz.y = bo[2 * tz + 1];

    const float* Bn = B + (size_t)n * LL * CH;
    v2f* outr = (v2f*)(out + (size_t)r * LL * CZ);

    const int j0 = tj * 96;
    for (int jj = 0; jj < 96; jj += 2) {
        const int ja = j0 + jj;
        const int jb = ja + 1;
        const v4f* bra = (const v4f*)(Bn + ja * CH);
        const v4f* brb = (const v4f*)(Bn + jb * CH);
        v4f a0[8], a1[8];
        #pragma unroll
        for (int q = 0; q < 8; ++q) a0[q] = bra[q];
        #pragma unroll
        for (int q = 0; q < 8; ++q) a1[q] = brb[q];

        v2f acc0 = bz, acc1 = bz;
        #pragma unroll
        for (int q = 0; q < 8; ++q) {
            acc0 += a0[q].x * m[4*q+0];
            acc0 += a0[q].y * m[4*q+1];
            acc0 += a0[q].z * m[4*q+2];
            acc0 += a0[q].w * m[4*q+3];
        }
        #pragma unroll
        for (int q = 0; q < 8; ++q) {
            acc1 += a1[q].x * m[4*q+0];
            acc1 += a1[q].y * m[4*q+1];
            acc1 += a1[q].z * m[4*q+2];
            acc1 += a1[q].w * m[4*q+3];
        }
        __builtin_nontemporal_store(acc0, &outr[(size_t)ja * 64 + tz]);
        __builtin_nontemporal_store(acc1, &outr[(size_t)jb * 64 + tz]);
    }
}

extern "C" void kernel_launch(void* const* d_in, const int* in_sizes, int n_in,
                              void* d_out, int out_size, void* d_ws, size_t ws_size,
                              hipStream_t stream) {
    const float* s  = (const float*)d_in[0];
    const float* g  = (const float*)d_in[1];
    const float* be = (const float*)d_in[2];
    const float* W1 = (const float*)d_in[3];
    const float* b1 = (const float*)d_in[4];
    const float* W2 = (const float*)d_in[5];
    const float* b2 = (const float*)d_in[6];
    const float* Wo = (const float*)d_in[7];
    const float* bo = (const float*)d_in[8];
    float* out = (float*)d_out;

    const size_t nA = (size_t)NL * CH;
    const size_t nM = (size_t)NL * CH * CZ;
    if (ws_size < (nA * 2 + nM) * sizeof(float)) return;  // fail visibly, no UB

    float* A  = (float*)d_ws;
    float* Bm = A + nA;
    float* M  = Bm + nA;

    k_ln_ab<<<NL, 128, 0, stream>>>(s, g, be, W1, b1, W2, b2, A, Bm);
    k_m   <<<NL / 16, 256, 0, stream>>>(A, Wo, M);
    k_out <<<NL, 256, 0, stream>>>(Bm, M, bo, out);
}

// Round 5
// 107.415 us; speedup vs baseline: 2.0445x; 2.0445x over previous
//
#include <hip/hip_runtime.h>
#include <hip/hip_bf16.h>

#define CS 384
#define CH 32
#define CZ 128
#define LL 384
#define NL 1536   // N*L
#define EPS 1e-5f

typedef float v2f __attribute__((ext_vector_type(2)));
typedef float v4f __attribute__((ext_vector_type(4)));

// ---------------- Kernel 1: LayerNorm + A = sn@W1+b1, B = sn@W2+b2 ------------
__global__ __launch_bounds__(128) void k_ln_ab(
    const float* __restrict__ s, const float* __restrict__ g, const float* __restrict__ be,
    const float* __restrict__ W1, const float* __restrict__ b1,
    const float* __restrict__ W2, const float* __restrict__ b2,
    float* __restrict__ A, float* __restrict__ B)
{
    const int row = blockIdx.x;
    const int t   = threadIdx.x;
    const int wid = t >> 6, lane = t & 63;
    const float* srow = s + (size_t)row * CS;

    __shared__ float sn[CS];
    __shared__ float red[2];
    __shared__ float part[128];

    float x0 = srow[t], x1 = srow[t + 128], x2 = srow[t + 256];

    // mean
    float p = x0 + x1 + x2;
    #pragma unroll
    for (int o = 32; o > 0; o >>= 1) p += __shfl_down(p, o);
    if (lane == 0) red[wid] = p;
    __syncthreads();
    const float mu = (red[0] + red[1]) * (1.0f / CS);
    __syncthreads();

    // variance
    float d0 = x0 - mu, d1 = x1 - mu, d2 = x2 - mu;
    float q = d0 * d0 + d1 * d1 + d2 * d2;
    #pragma unroll
    for (int o = 32; o > 0; o >>= 1) q += __shfl_down(q, o);
    if (lane == 0) red[wid] = q;
    __syncthreads();
    const float var = (red[0] + red[1]) * (1.0f / CS);
    const float rstd = rsqrtf(var + EPS);

    sn[t]       = d0 * rstd * g[t]       + be[t];
    sn[t + 128] = d1 * rstd * g[t + 128] + be[t + 128];
    sn[t + 256] = d2 * rstd * g[t + 256] + be[t + 256];
    __syncthreads();

    // matvec: all 128 threads. t -> (half = t>>6, mat = (t>>5)&1, h = t&31)
    {
        const int h    = t & 31;
        const int mat  = (t >> 5) & 1;
        const int half = t >> 6;
        const float* W = mat ? W2 : W1;
        float acc = 0.0f;
        const int c0 = half * (CS / 2);
        #pragma unroll 8
        for (int c = c0; c < c0 + CS / 2; ++c)
            acc += sn[c] * W[c * CH + h];
        part[t] = acc;
    }
    __syncthreads();
    if (t < 64) {
        const int h   = t & 31;
        const int mat = t >> 5;
        const float v = part[t] + part[t + 64] + (mat ? b2[h] : b1[h]);
        (mat ? B : A)[(size_t)row * CH + h] = v;
    }
}

// ---------------- Kernel 2: M[r,d,z] = sum_c A[r,c] * Wo[c,d,z] --------------
// GEMM: [NL,32] x [32,4096] -> [NL,4096]; 4 rows/block, 384 blocks.
__global__ __launch_bounds__(256) void k_m(
    const float* __restrict__ A, const float* __restrict__ Wo, float* __restrict__ M)
{
    const int t  = threadIdx.x;
    const int r0 = blockIdx.x * 4;
    __shared__ float Al[4][CH];
    if (t < 128) Al[t >> 5][t & 31] = A[(size_t)(r0 + (t >> 5)) * CH + (t & 31)];
    __syncthreads();

    const v4f* Wo4 = (const v4f*)Wo;      // 1024 float4 per c-row
    v4f*       M4  = (v4f*)M;

    for (int g4 = t; g4 < 1024; g4 += 256) {
        v4f acc[4];
        #pragma unroll
        for (int r = 0; r < 4; ++r) acc[r] = (v4f)(0.f);
        #pragma unroll 8
        for (int c = 0; c < CH; ++c) {
            const v4f wv = Wo4[(size_t)c * 1024 + g4];
            #pragma unroll
            for (int r = 0; r < 4; ++r)
                acc[r] += Al[r][c] * wv;
        }
        #pragma unroll
        for (int r = 0; r < 4; ++r)
            M4[(size_t)(r0 + r) * 1024 + g4] = acc[r];
    }
}

// ---------------- Kernel 3: out[r,j,z] = sum_d B[n,j,d]*M[r,d,z] + bo[z] -----
// Grid (NL, 4): block = 1 wave, owns r and a 96-wide j-chunk. Thread tz owns
// z-pair -> m[32] v2f (64 VGPR) held in registers (launch_bounds(64,1) lifts
// the VGPR cap). Ping-pong prefetch of b-rows so stores never sit in a load's
// vmcnt wait set. Plain (cached) stores -> L2 absorbs, no NT serialization.
__global__ __launch_bounds__(64, 1) void k_out(
    const float* __restrict__ B, const float* __restrict__ M,
    const float* __restrict__ bo, float* __restrict__ out)
{
    const int r  = blockIdx.x;
    const int jc = blockIdx.y;      // 0..3
    const int tz = threadIdx.x;     // 0..63, z = 2*tz
    const int n  = r / LL;

    v2f m[CH];
    {
        const v2f* Mr = (const v2f*)(M + (size_t)r * (CH * CZ));
        #pragma unroll
        for (int d = 0; d < CH; ++d) m[d] = Mr[d * 64 + tz];
    }
    const v2f bz = ((const v2f*)bo)[tz];

    const v4f* Bj = (const v4f*)(B + (size_t)n * LL * CH) + (size_t)(jc * 96) * 8;
    v2f* outr = (v2f*)(out + (size_t)r * LL * CZ) + (size_t)(jc * 96) * 64;

    v4f bA[8], bB[8];
    #pragma unroll
    for (int q = 0; q < 8; ++q) bA[q] = Bj[q];

    for (int jj = 0; jj < 96; jj += 2) {
        // prefetch jj+1 into bB (issued before the store of jj)
        #pragma unroll
        for (int q = 0; q < 8; ++q) bB[q] = Bj[(size_t)(jj + 1) * 8 + q];

        v2f acc = bz;
        #pragma unroll
        for (int q = 0; q < 8; ++q) {
            acc += bA[q].x * m[4*q+0];
            acc += bA[q].y * m[4*q+1];
            acc += bA[q].z * m[4*q+2];
            acc += bA[q].w * m[4*q+3];
        }
        outr[(size_t)jj * 64 + tz] = acc;

        // prefetch jj+2 into bA
        if (jj + 2 < 96) {
            #pragma unroll
            for (int q = 0; q < 8; ++q) bA[q] = Bj[(size_t)(jj + 2) * 8 + q];
        }

        acc = bz;
        #pragma unroll
        for (int q = 0; q < 8; ++q) {
            acc += bB[q].x * m[4*q+0];
            acc += bB[q].y * m[4*q+1];
            acc += bB[q].z * m[4*q+2];
            acc += bB[q].w * m[4*q+3];
        }
        outr[(size_t)(jj + 1) * 64 + tz] = acc;
    }
}

extern "C" void kernel_launch(void* const* d_in, const int* in_sizes, int n_in,
                              void* d_out, int out_size, void* d_ws, size_t ws_size,
                              hipStream_t stream) {
    const float* s  = (const float*)d_in[0];
    const float* g  = (const float*)d_in[1];
    const float* be = (const float*)d_in[2];
    const float* W1 = (const float*)d_in[3];
    const float* b1 = (const float*)d_in[4];
    const float* W2 = (const float*)d_in[5];
    const float* b2 = (const float*)d_in[6];
    const float* Wo = (const float*)d_in[7];
    const float* bo = (const float*)d_in[8];
    float* out = (float*)d_out;

    const size_t nA = (size_t)NL * CH;
    const size_t nM = (size_t)NL * CH * CZ;
    if (ws_size < (nA * 2 + nM) * sizeof(float)) return;  // fail visibly, no UB

    float* A  = (float*)d_ws;
    float* Bm = A + nA;
    float* M  = Bm + nA;

    k_ln_ab<<<NL, 128, 0, stream>>>(s, g, be, W1, b1, W2, b2, A, Bm);
    k_m   <<<NL / 4, 256, 0, stream>>>(A, Wo, M);
    dim3 gout(NL, 4);
    k_out <<<gout, 64, 0, stream>>>(Bm, M, bo, out);
}